// Round 7
// baseline (104.333 us; speedup 1.0000x reference)
//
#include <hip/hip_runtime.h>

#define L_LEAVES 8192
#define W_LAMBDA 2101
#define QPL      526               // quads per leaf = ceil(2101/4)
#define WPAD     2104              // padded table stride (16B-aligned rows)
#define SA2_40   0.41317591116653485f
#define LOG2E_F  1.4426950408889634f
#define LN2_F    0.6931471805599453f

__device__ __forceinline__ float rcpf(float x)  { return __builtin_amdgcn_rcpf(x); }
__device__ __forceinline__ float log2f_fast(float x) { return __builtin_amdgcn_logf(x); }   // v_log_f32 = log2
__device__ __forceinline__ float exp2f_fast(float x) { return __builtin_amdgcn_exp2f(x); }  // v_exp_f32 = 2^x
__device__ __forceinline__ float sqrtf_fast(float x) { return __builtin_amdgcn_sqrtf(x); }

// ---- transmissivity of a dielectric plane (Stern / Allen), per-wavelength ----
__device__ __forceinline__ float getav_dev(float sa2, bool is90, float nr) {
    float n2  = nr * nr;
    float npx = n2 + 1.0f;
    float nm  = n2 - 1.0f;
    float a   = (nr + 1.0f) * (nr + 1.0f) * 0.5f;
    float k   = -(n2 - 1.0f) * (n2 - 1.0f) * 0.25f;
    float b2  = sa2 - npx * 0.5f;
    float b1  = is90 ? 0.0f : sqrtf(b2 * b2 + k);
    float b   = b1 - b2;
    float k2  = k * k;
    float b3  = b * b * b;
    float a3  = a * a * a;
    float ts  = k2 / (6.0f * b3) + k / b - b * 0.5f
              - (k2 / (6.0f * a3) + k / a - a * 0.5f);
    float tp1 = -2.0f * n2 * (b - a) / (npx * npx);
    float nm2 = nm * nm;
    float tp2 = -2.0f * n2 * npx * logf(b / a) / nm2;
    float tp3 = n2 * (1.0f / b - 1.0f / a) * 0.5f;
    float n22 = n2 * n2;
    float npx3 = npx * npx * npx;
    float npax_a = 2.0f * npx * a - nm2;
    float npx_b  = 2.0f * npx * b - nm2;
    float tp4 = 16.0f * n22 * (n22 + 1.0f) * logf(npx_b / npax_a) / (npx3 * nm2);
    float tp5 = 16.0f * n2 * n2 * n2 * (1.0f / npx_b - 1.0f / npax_a) / npx3;
    float tp  = tp1 + tp2 + tp3 + tp4 + tp5;
    return (ts + tp) / (2.0f * sa2);
}

// per-wavelength table rows: 0: talf*t21  1: ralf  2: t12*t21  3: r12  4: r21
__global__ void precompute_kernel(const float* __restrict__ nr, float* __restrict__ tab) {
    int w = blockIdx.x * blockDim.x + threadIdx.x;
    if (w >= W_LAMBDA) return;
    float n    = nr[w];
    float talf = getav_dev(SA2_40, false, n);
    float t12  = getav_dev(1.0f,   true,  n);
    float t21  = t12 * rcpf(n * n);
    float r21  = 1.0f - t21;
    tab[0 * WPAD + w] = talf * t21;
    tab[1 * WPAD + w] = 1.0f - talf;
    tab[2 * WPAD + w] = t12 * t21;
    tab[3 * WPAD + w] = 1.0f - t12;
    tab[4 * WPAD + w] = r21;
}

struct f4u { float v[4]; };  // 4B-aligned vec4 store (rows start at l*2101 floats)

__device__ __forceinline__ float vget(const float4& v, int j) {
    return j == 0 ? v.x : (j == 1 ? v.y : (j == 2 ? v.z : v.w));
}

template<bool USE_TAB>
__global__ __launch_bounds__(256) void prospect_kernel(
    const float* __restrict__ pN,   const float* __restrict__ pcab,
    const float* __restrict__ pcar, const float* __restrict__ pwater,
    const float* __restrict__ plma, const float* __restrict__ pcant,
    const float* __restrict__ pnr,
    const float* __restrict__ pkab, const float* __restrict__ pkcar,
    const float* __restrict__ pkant, const float* __restrict__ pkw,
    const float* __restrict__ pkm,
    const float* __restrict__ tab,
    float* __restrict__ out_r, float* __restrict__ out_t)
{
    // flattened: one quad of wavelengths per thread, zero grid tail
    const int q  = blockIdx.x * 256 + threadIdx.x;   // global quad id, < 8192*526
    const int l  = q / QPL;                          // leaf (magic-mul div)
    const int w0 = (q - l * QPL) * 4;
    const bool full = (w0 + 4 <= W_LAMBDA);

    const float Nl   = pN[l];
    const float invN = rcpf(Nl);
    const float Nm1  = Nl - 1.0f;
    const float cabl = pcab[l], carl = pcar[l], cantl = pcant[l];
    const float watl = pwater[l], lmal = plma[l];

    float4 vkab, vkcar, vkant, vkw, vkm;
    float4 t0, t1, t2, t3, t4;
    if (full) {
        vkab  = *(const float4*)(pkab  + w0);
        vkcar = *(const float4*)(pkcar + w0);
        vkant = *(const float4*)(pkant + w0);
        vkw   = *(const float4*)(pkw   + w0);
        vkm   = *(const float4*)(pkm   + w0);
    } else {
        #pragma unroll
        for (int j = 0; j < 4; ++j) {
            int w = min(w0 + j, W_LAMBDA - 1);
            ((float*)&vkab)[j]  = pkab[w];
            ((float*)&vkcar)[j] = pkcar[w];
            ((float*)&vkant)[j] = pkant[w];
            ((float*)&vkw)[j]   = pkw[w];
            ((float*)&vkm)[j]   = pkm[w];
        }
    }
    if (USE_TAB) {
        // tab rows padded to WPAD: float4 at w0<=2100 stays in-bounds
        t0 = *(const float4*)(tab + 0 * WPAD + w0);
        t1 = *(const float4*)(tab + 1 * WPAD + w0);
        t2 = *(const float4*)(tab + 2 * WPAD + w0);
        t3 = *(const float4*)(tab + 3 * WPAD + w0);
        t4 = *(const float4*)(tab + 4 * WPAD + w0);
    } else {
        #pragma unroll
        for (int j = 0; j < 4; ++j) {
            int w = min(w0 + j, W_LAMBDA - 1);
            float n    = pnr[w];
            float talf = getav_dev(SA2_40, false, n);
            float t12  = getav_dev(1.0f,   true,  n);
            float t21  = t12 * rcpf(n * n);
            float r21  = 1.0f - t21;
            ((float*)&t0)[j] = talf * t21;
            ((float*)&t1)[j] = 1.0f - talf;
            ((float*)&t2)[j] = t12 * t21;
            ((float*)&t3)[j] = 1.0f - t12;
            ((float*)&t4)[j] = r21;
        }
    }

    float rf[4], tr[4];
    #pragma unroll
    for (int j = 0; j < 4; ++j) {
        const float c0 = vget(t0, j), c1 = vget(t1, j), c2 = vget(t2, j);
        const float c3 = vget(t3, j), c4 = vget(t4, j);

        // absorption coefficient
        float k = (cabl * vget(vkab, j) + carl * vget(vkcar, j) + cantl * vget(vkant, j)
                 + watl * vget(vkw, j) + lmal * vget(vkm, j)) * invN;
        k = fmaxf(k, 1e-4f);

        // tau = (1-k)e^{-k} + k^2 E1(k)
        float ek   = exp2f_fast(-k * LOG2E_F);
        float lg2k = log2f_fast(k);
        float poly = fmaf(fmaf(fmaf(fmaf(fmaf(0.00107857f, k, -0.00976004f), k, 0.05519968f),
                        k, -0.24991055f), k, 0.99999193f), k, -0.57721566f);
        float e1s  = fmaf(-LN2_F, lg2k, poly);
        float taus = fmaf(k * k, e1s, fmaf(-k, ek, ek));     // (1-k)ek + k^2 e1s
        float pn = fmaf(fmaf(fmaf(k + 8.5733287401f, k, 18.0590169730f),
                       k, 8.6347608925f), k, 0.2677737343f);
        float pd = fmaf(fmaf(fmaf(k + 9.5733223454f, k, 25.6329561486f),
                       k, 21.0996530827f), k, 3.9584969228f);
        float taub = ek * fmaf(k, pn - pd, pd) * rcpf(pd);   // ek*(pd+k(pn-pd))/pd
        float tau  = (k <= 1.0f) ? taus : taub;

        // one-layer R/T; denom from (r21*tau)^2
        float r21t = c4 * tau;
        float rd   = rcpf(fmaf(-r21t, r21t, 1.0f));  // 1/(1 - r21^2 tau^2)
        float trd  = tau * rd;
        float Ta   = c0 * trd;                       // talf*t21 * tau / denom
        float tt   = c2 * trd;                       // t12*t21  * tau / denom
        float Ra   = fmaf(r21t, Ta, c1);
        float rr   = fmaf(r21t, tt, c3);

        // Stokes N-1 layers (den2*den3 merged into M)
        float rpt  = rr + tt;
        float rmt  = rr - tt;
        bool  mask = (rpt >= 1.0f);
        float Dsq  = fmaf(-rmt, rmt, 1.0f) * fmaf(-rpt, rpt, 1.0f);
        float D    = sqrtf_fast(mask ? 1.0f : Dsq);
        float rq   = rpt * rmt;                      // r^2 - t^2
        float s1   = 1.0f + D;
        float rp2  = rcpf((rr * tt) * 4.0f);         // pair-reciprocal 1/(2r),1/(2t)
        float aa   = (s1 + rq) * (rp2 * (tt + tt));
        float bb   = (s1 - rq) * (rp2 * (rr + rr));
        float bsafe = mask ? 1.0f : bb;
        float bnm1 = exp2f_fast(Nm1 * log2f_fast(bsafe));   // b^(N-1)
        float bn2  = bnm1 * bnm1;
        float a2   = aa * aa;
        float den2 = fmaf(a2, bn2, -1.0f);           // a^2 b^{2n} - 1
        float bn2m1 = bn2 - 1.0f;
        float M    = fmaf(-aa * rr, bn2m1, den2);    // den2 - a r (b^{2n}-1) = den2*den3
        float invM = rcpf(M);
        float TaM  = Ta * invM;
        float tranj = TaM * bnm1 * (a2 - 1.0f);      // Ta*Tsub/den3
        float reflj = fmaf(TaM * tt * aa, bn2m1, Ra);// Ra + Ta*Rsub*t/den3

        if (__any((int)mask)) {                      // thick-leaf branch (rare)
            float Talt = tt * rcpf(fmaf(Nm1, 1.0f - tt, tt));
            float Rsm  = 1.0f - Talt;
            float g    = Ta * rcpf(fmaf(-Rsm, rr, 1.0f));
            if (mask) { tranj = g * Talt; reflj = fmaf(g * Rsm, tt, Ra); }
        }

        tr[j] = tranj;
        rf[j] = reflj;
    }

    const unsigned base = (unsigned)l * W_LAMBDA + (unsigned)w0;
    if (full) {
        f4u fr; f4u ft;
        #pragma unroll
        for (int j = 0; j < 4; ++j) { fr.v[j] = rf[j]; ft.v[j] = tr[j]; }
        *reinterpret_cast<f4u*>(out_r + base) = fr;
        *reinterpret_cast<f4u*>(out_t + base) = ft;
    } else {
        out_r[base] = rf[0];
        out_t[base] = tr[0];
    }
}

extern "C" void kernel_launch(void* const* d_in, const int* in_sizes, int n_in,
                              void* d_out, int out_size, void* d_ws, size_t ws_size,
                              hipStream_t stream) {
    const float* pN     = (const float*)d_in[0];
    const float* pcab   = (const float*)d_in[1];
    const float* pcar   = (const float*)d_in[2];
    const float* pwater = (const float*)d_in[3];
    const float* plma   = (const float*)d_in[4];
    const float* pcant  = (const float*)d_in[5];
    const float* pnr    = (const float*)d_in[6];
    const float* pkab   = (const float*)d_in[7];
    const float* pkcar  = (const float*)d_in[8];
    const float* pkant  = (const float*)d_in[9];
    const float* pkw    = (const float*)d_in[10];
    const float* pkm    = (const float*)d_in[11];
    float* out_r = (float*)d_out;
    float* out_t = out_r + (size_t)L_LEAVES * W_LAMBDA;

    const int nquads = L_LEAVES * QPL;                 // 4,308,992 = 256 * 16832
    dim3 grid(nquads / 256);
    dim3 block(256);

    const size_t tab_bytes = 5 * WPAD * sizeof(float);
    if (ws_size >= tab_bytes) {
        float* tabp = (float*)d_ws;
        precompute_kernel<<<(W_LAMBDA + 255) / 256, 256, 0, stream>>>(pnr, tabp);
        prospect_kernel<true><<<grid, block, 0, stream>>>(
            pN, pcab, pcar, pwater, plma, pcant, pnr,
            pkab, pkcar, pkant, pkw, pkm, (const float*)tabp, out_r, out_t);
    } else {
        prospect_kernel<false><<<grid, block, 0, stream>>>(
            pN, pcab, pcar, pwater, plma, pcant, pnr,
            pkab, pkcar, pkant, pkw, pkm, nullptr, out_r, out_t);
    }
}

// Round 8
// 56.189 us; speedup vs baseline: 1.8568x; 1.8568x over previous
//
#include <hip/hip_runtime.h>

#define L_LEAVES 8192
#define W_LAMBDA 2101
#define WPAD     2104              // padded table stride (16B-aligned rows)
#define TAB_N    1153              // tau table: 18 octaves * 64 + 1 fencepost (k in [2^-14, 16])
#define SA2_40   0.41317591116653485f
#define LOG2E_F  1.4426950408889634f
#define LN2_F    0.6931471805599453f

__device__ __forceinline__ float rcpf(float x)  { return __builtin_amdgcn_rcpf(x); }
__device__ __forceinline__ float log2f_fast(float x) { return __builtin_amdgcn_logf(x); }
__device__ __forceinline__ float exp2f_fast(float x) { return __builtin_amdgcn_exp2f(x); }
__device__ __forceinline__ float sqrtf_fast(float x) { return __builtin_amdgcn_sqrtf(x); }

// ---- transmissivity of a dielectric plane (Stern / Allen), per-wavelength ----
__device__ __forceinline__ float getav_dev(float sa2, bool is90, float nr) {
    float n2  = nr * nr;
    float npx = n2 + 1.0f;
    float nm  = n2 - 1.0f;
    float a   = (nr + 1.0f) * (nr + 1.0f) * 0.5f;
    float k   = -(n2 - 1.0f) * (n2 - 1.0f) * 0.25f;
    float b2  = sa2 - npx * 0.5f;
    float b1  = is90 ? 0.0f : sqrtf(b2 * b2 + k);
    float b   = b1 - b2;
    float k2  = k * k;
    float b3  = b * b * b;
    float a3  = a * a * a;
    float ts  = k2 / (6.0f * b3) + k / b - b * 0.5f
              - (k2 / (6.0f * a3) + k / a - a * 0.5f);
    float tp1 = -2.0f * n2 * (b - a) / (npx * npx);
    float nm2 = nm * nm;
    float tp2 = -2.0f * n2 * npx * logf(b / a) / nm2;
    float tp3 = n2 * (1.0f / b - 1.0f / a) * 0.5f;
    float n22 = n2 * n2;
    float npx3 = npx * npx * npx;
    float npax_a = 2.0f * npx * a - nm2;
    float npx_b  = 2.0f * npx * b - nm2;
    float tp4 = 16.0f * n22 * (n22 + 1.0f) * logf(npx_b / npax_a) / (npx3 * nm2);
    float tp5 = 16.0f * n2 * n2 * n2 * (1.0f / npx_b - 1.0f / npax_a) / npx3;
    float tp  = tp1 + tp2 + tp3 + tp4 + tp5;
    return (ts + tp) / (2.0f * sa2);
}

// precise tau(k) for table construction (libm expf/logf)
__device__ __forceinline__ float tau_exact(float k) {
    float ek = expf(-k);
    float e1;
    if (k <= 1.0f) {
        float poly = fmaf(fmaf(fmaf(fmaf(fmaf(0.00107857f, k, -0.00976004f), k, 0.05519968f),
                        k, -0.24991055f), k, 0.99999193f), k, -0.57721566f);
        e1 = -logf(k) + poly;
    } else {
        float pn = fmaf(fmaf(fmaf(k + 8.5733287401f, k, 18.0590169730f),
                       k, 8.6347608925f), k, 0.2677737343f);
        float pd = fmaf(fmaf(fmaf(k + 9.5733223454f, k, 25.6329561486f),
                       k, 21.0996530827f), k, 3.9584969228f);
        e1 = ek / k * (pn / pd);
    }
    return (1.0f - k) * ek + k * k * e1;
}

// d_ws layout: rows 0..4 (WPAD each): talf*t21, ralf, t12*t21, r12, r21 ; then tauTab[TAB_N]
__global__ void precompute_kernel(const float* __restrict__ nr, float* __restrict__ tab) {
    int w = blockIdx.x * blockDim.x + threadIdx.x;
    if (w < WPAD) {                           // fill pad with clones of last column
        int ws = min(w, W_LAMBDA - 1);
        float n    = nr[ws];
        float talf = getav_dev(SA2_40, false, n);
        float t12  = getav_dev(1.0f,   true,  n);
        float t21  = t12 / (n * n);
        float r21  = 1.0f - t21;
        tab[0 * WPAD + w] = talf * t21;
        tab[1 * WPAD + w] = 1.0f - talf;
        tab[2 * WPAD + w] = t12 * t21;
        tab[3 * WPAD + w] = 1.0f - t12;
        tab[4 * WPAD + w] = r21;
    }
    if (w < TAB_N) {                          // tau table, bit-pattern log-spaced bins
        unsigned e = (unsigned)w >> 6, m = (unsigned)w & 63u;
        unsigned bits = ((113u + e) << 23) | (m << 17);
        float k = __uint_as_float(bits);
        tab[5 * WPAD + w] = tau_exact(k);
    }
}

struct f4u { float v[4]; };  // 4B-aligned vec4 store (rows start at l*2101 floats)

__device__ __forceinline__ float vget(const float4& v, int j) {
    return j == 0 ? v.x : (j == 1 ? v.y : (j == 2 ? v.z : v.w));
}

template<bool USE_TAB>
__global__ __launch_bounds__(192) void prospect_kernel(
    const float* __restrict__ pN,   const float* __restrict__ pcab,
    const float* __restrict__ pcar, const float* __restrict__ pwater,
    const float* __restrict__ plma, const float* __restrict__ pcant,
    const float* __restrict__ pnr,
    const float* __restrict__ pkab, const float* __restrict__ pkcar,
    const float* __restrict__ pkant, const float* __restrict__ pkw,
    const float* __restrict__ pkm,
    const float* __restrict__ tab,
    float* __restrict__ out_r, float* __restrict__ out_t)
{
    __shared__ float TT[TAB_N];
    if (USE_TAB) {
        for (int i = threadIdx.x; i < TAB_N; i += 192)
            TT[i] = tab[5 * WPAD + i];
        __syncthreads();
    }

    const int q  = blockIdx.x * 192 + threadIdx.x;   // quad-of-wavelengths in leaf
    const int w0 = q * 4;
    if (w0 >= W_LAMBDA) return;
    const bool full = (w0 + 4 <= W_LAMBDA);

    const int l = blockIdx.y;          // leaf: wave-uniform -> SGPR trait loads
    const float Nl   = pN[l];
    const float invN = rcpf(Nl);
    const float Nm1  = Nl - 1.0f;
    const float cabl = pcab[l], carl = pcar[l], cantl = pcant[l];
    const float watl = pwater[l], lmal = plma[l];

    float4 vkab, vkcar, vkant, vkw, vkm;
    if (full) {
        vkab  = *(const float4*)(pkab  + w0);
        vkcar = *(const float4*)(pkcar + w0);
        vkant = *(const float4*)(pkant + w0);
        vkw   = *(const float4*)(pkw   + w0);
        vkm   = *(const float4*)(pkm   + w0);
    } else {
        #pragma unroll
        for (int j = 0; j < 4; ++j) {
            int w = min(w0 + j, W_LAMBDA - 1);
            ((float*)&vkab)[j]  = pkab[w];
            ((float*)&vkcar)[j] = pkcar[w];
            ((float*)&vkant)[j] = pkant[w];
            ((float*)&vkw)[j]   = pkw[w];
            ((float*)&vkm)[j]   = pkm[w];
        }
    }
    float4 t0, t1, t2, t3, t4;
    if (USE_TAB) {
        // rows padded to WPAD with valid clones -> float4 always in-bounds & sane
        t0 = *(const float4*)(tab + 0 * WPAD + w0);
        t1 = *(const float4*)(tab + 1 * WPAD + w0);
        t2 = *(const float4*)(tab + 2 * WPAD + w0);
        t3 = *(const float4*)(tab + 3 * WPAD + w0);
        t4 = *(const float4*)(tab + 4 * WPAD + w0);
    } else {
        #pragma unroll
        for (int j = 0; j < 4; ++j) {
            int w = min(w0 + j, W_LAMBDA - 1);
            float n    = pnr[w];
            float talf = getav_dev(SA2_40, false, n);
            float t12  = getav_dev(1.0f,   true,  n);
            float t21  = t12 * rcpf(n * n);
            float r21  = 1.0f - t21;
            ((float*)&t0)[j] = talf * t21;
            ((float*)&t1)[j] = 1.0f - talf;
            ((float*)&t2)[j] = t12 * t21;
            ((float*)&t3)[j] = 1.0f - t12;
            ((float*)&t4)[j] = r21;
        }
    }

    float rf[4], tr[4];
    #pragma unroll
    for (int j = 0; j < 4; ++j) {
        const float c0 = vget(t0, j), c1 = vget(t1, j), c2 = vget(t2, j);
        const float c3 = vget(t3, j), c4 = vget(t4, j);

        // absorption coefficient
        float k = (cabl * vget(vkab, j) + carl * vget(vkcar, j) + cantl * vget(vkant, j)
                 + watl * vget(vkw, j) + lmal * vget(vkm, j)) * invN;
        k = fmaxf(k, 1e-4f);

        float tau;
        if (USE_TAB) {
            // tau(k) via bit-indexed piecewise-linear LDS table
            float kc = fminf(k, 15.9f);
            unsigned bits = __float_as_uint(kc);
            int idx = (int)(bits >> 17) - 7232;          // 113<<6
            float frac = (float)(bits & 0x1FFFFu) * (1.0f / 131072.0f);
            float T0 = TT[idx];
            float T1 = TT[idx + 1];
            tau = fmaf(frac, T1 - T0, T0);
        } else {
            float ek   = exp2f_fast(-k * LOG2E_F);
            float lg2k = log2f_fast(k);
            float poly = fmaf(fmaf(fmaf(fmaf(fmaf(0.00107857f, k, -0.00976004f), k, 0.05519968f),
                            k, -0.24991055f), k, 0.99999193f), k, -0.57721566f);
            float e1s  = fmaf(-LN2_F, lg2k, poly);
            float taus = fmaf(k * k, e1s, fmaf(-k, ek, ek));
            float pn = fmaf(fmaf(fmaf(k + 8.5733287401f, k, 18.0590169730f),
                           k, 8.6347608925f), k, 0.2677737343f);
            float pd = fmaf(fmaf(fmaf(k + 9.5733223454f, k, 25.6329561486f),
                           k, 21.0996530827f), k, 3.9584969228f);
            float taub = ek * fmaf(k, pn - pd, pd) * rcpf(pd);
            tau  = (k <= 1.0f) ? taus : taub;
        }

        // one-layer R/T; denom from (r21*tau)^2
        float r21t = c4 * tau;
        float rd   = rcpf(fmaf(-r21t, r21t, 1.0f));  // 1/(1 - r21^2 tau^2)
        float trd  = tau * rd;
        float Ta   = c0 * trd;                       // talf*t21 * tau / denom
        float tt   = c2 * trd;                       // t12*t21  * tau / denom
        float Ra   = fmaf(r21t, Ta, c1);
        float rr   = fmaf(r21t, tt, c3);

        // Stokes N-1 layers (den2*den3 merged into M)
        float rpt  = rr + tt;
        float rmt  = rr - tt;
        bool  mask = (rpt >= 1.0f);
        float Dsq  = fmaf(-rmt, rmt, 1.0f) * fmaf(-rpt, rpt, 1.0f);
        float D    = sqrtf_fast(mask ? 1.0f : Dsq);
        float rq   = rpt * rmt;                      // r^2 - t^2
        float s1   = 1.0f + D;
        float rp2  = rcpf((rr * tt) * 4.0f);         // pair-reciprocal 1/(2r),1/(2t)
        float aa   = (s1 + rq) * (rp2 * (tt + tt));
        float bb   = (s1 - rq) * (rp2 * (rr + rr));
        float bsafe = mask ? 1.0f : bb;
        float bnm1 = exp2f_fast(Nm1 * log2f_fast(bsafe));   // b^(N-1)
        float bn2  = bnm1 * bnm1;
        float a2   = aa * aa;
        float den2 = fmaf(a2, bn2, -1.0f);           // a^2 b^{2n} - 1
        float bn2m1 = bn2 - 1.0f;
        float M    = fmaf(-aa * rr, bn2m1, den2);    // den2 - a r (b^{2n}-1) = den2*den3
        float invM = rcpf(M);
        float TaM  = Ta * invM;
        float tranj = TaM * bnm1 * (a2 - 1.0f);      // Ta*Tsub/den3
        float reflj = fmaf(TaM * tt * aa, bn2m1, Ra);// Ra + Ta*Rsub*t/den3

        if (__any((int)mask)) {                      // thick-leaf branch (rare)
            float Talt = tt * rcpf(fmaf(Nm1, 1.0f - tt, tt));
            float Rsm  = 1.0f - Talt;
            float g    = Ta * rcpf(fmaf(-Rsm, rr, 1.0f));
            if (mask) { tranj = g * Talt; reflj = fmaf(g * Rsm, tt, Ra); }
        }

        tr[j] = tranj;
        rf[j] = reflj;
    }

    const unsigned base = (unsigned)l * W_LAMBDA + (unsigned)w0;
    if (full) {
        f4u fr; f4u ft;
        #pragma unroll
        for (int j = 0; j < 4; ++j) { fr.v[j] = rf[j]; ft.v[j] = tr[j]; }
        *reinterpret_cast<f4u*>(out_r + base) = fr;
        *reinterpret_cast<f4u*>(out_t + base) = ft;
    } else {
        out_r[base] = rf[0];
        out_t[base] = tr[0];
    }
}

extern "C" void kernel_launch(void* const* d_in, const int* in_sizes, int n_in,
                              void* d_out, int out_size, void* d_ws, size_t ws_size,
                              hipStream_t stream) {
    const float* pN     = (const float*)d_in[0];
    const float* pcab   = (const float*)d_in[1];
    const float* pcar   = (const float*)d_in[2];
    const float* pwater = (const float*)d_in[3];
    const float* plma   = (const float*)d_in[4];
    const float* pcant  = (const float*)d_in[5];
    const float* pnr    = (const float*)d_in[6];
    const float* pkab   = (const float*)d_in[7];
    const float* pkcar  = (const float*)d_in[8];
    const float* pkant  = (const float*)d_in[9];
    const float* pkw    = (const float*)d_in[10];
    const float* pkm    = (const float*)d_in[11];
    float* out_r = (float*)d_out;
    float* out_t = out_r + (size_t)L_LEAVES * W_LAMBDA;

    const int nquads = (W_LAMBDA + 3) / 4;                 // 526
    dim3 grid((nquads + 191) / 192, L_LEAVES);             // (3, 8192)
    dim3 block(192);

    const size_t tab_bytes = (5 * WPAD + TAB_N) * sizeof(float);
    if (ws_size >= tab_bytes) {
        float* tabp = (float*)d_ws;
        precompute_kernel<<<(WPAD + 255) / 256, 256, 0, stream>>>(pnr, tabp);
        prospect_kernel<true><<<grid, block, 0, stream>>>(
            pN, pcab, pcar, pwater, plma, pcant, pnr,
            pkab, pkcar, pkant, pkw, pkm, (const float*)tabp, out_r, out_t);
    } else {
        prospect_kernel<false><<<grid, block, 0, stream>>>(
            pN, pcab, pcar, pwater, plma, pcant, pnr,
            pkab, pkcar, pkant, pkw, pkm, nullptr, out_r, out_t);
    }
}